// Round 8
// baseline (115.153 us; speedup 1.0000x reference)
//
#include <hip/hip_runtime.h>
#include <hip/hip_bf16.h>

// NodeToGlobal: per-graph segment {mean,min,max,std} over sorted batch ids,
// concat -> [G, 4D] -> @ W [4D, Gdim] + b.
// N=500000, D=256, G=8192, 4D=1024, Gdim=256.
//
// Pipelined fused design: prep builds B' (W in MFMA-octet bf16) + offsets.
// Main kernel: each block owns TWO 16-graph tiles with double-buffered LDS.
//   Phase A: stats(tile0) -> buf0.            (stream only)
//   Phase B: stats(tile1) -> buf1, with one GEMM(tile0) k-step injected per
//            8-row burst — MFMA + L2 B'-reads hide under HBM streaming.
//   Phase C: GEMM(tile1) drain (only exposed GEMM, ~half of before).
//
// Octet layout (coalesced MFMA fragments): X'[tile16][o][r][e] holds
// X[tile16*16 + r][o*8 + e].

#define DIM 256
#define NG 8192
#define KD 1024   // 4*DIM
#define NOUT 256  // g_dim

typedef __attribute__((ext_vector_type(8))) short bf16x8;
typedef __attribute__((ext_vector_type(4))) float f32x4;

__device__ __forceinline__ unsigned short f2bf(float x) {
    // round-to-nearest-even fp32 -> bf16 (finite inputs only)
    unsigned int u = __float_as_uint(x);
    u += 0x7fffu + ((u >> 16) & 1u);
    return (unsigned short)(u >> 16);
}

__device__ __forceinline__ unsigned int pack2(float a, float b) {
    return (unsigned int)f2bf(a) | ((unsigned int)f2bf(b) << 16);
}

// prep: blocks [0,64): W -> B' octet bf16 (LDS 64x64 transpose tiles);
//       blocks [64,97): offs[t] = lower_bound(batch, t), t in [0, 8192].
__global__ __launch_bounds__(256) void prep_kernel(const float* __restrict__ W,
                                                   const int* __restrict__ batch,
                                                   int N,
                                                   unsigned short* __restrict__ WT,
                                                   int* __restrict__ offs) {
    __shared__ float tile[64][68];

    if (blockIdx.x >= 64) {
        int t = ((int)blockIdx.x - 64) * 256 + (int)threadIdx.x;
        if (t > NG) return;
        // int64 detection: word[N-1] is the hi-word of element (N-1)/2 when
        // batch is int64 (== 0 since ids < 8192); for int32 it's the max id.
        const bool is64 = (batch[N - 1] == 0);
        int lo = 0, hi = N;
        while (lo < hi) {
            int mid = (lo + hi) >> 1;
            int v = is64 ? batch[2 * mid] : batch[mid];
            if (v < t) lo = mid + 1; else hi = mid;
        }
        offs[t] = lo;
        return;
    }

    // ---- W transpose + bf16 cast into B' octet layout ----
    const int t = threadIdx.x;
    const int tk0 = ((int)blockIdx.x & 15) * 64;  // 16 k-tiles
    const int tn0 = ((int)blockIdx.x >> 4) * 64;  // 4 n-tiles
    const int lk = t >> 2;
    const int ln = (t & 3) * 16;
#pragma unroll
    for (int j = 0; j < 16; j += 4) {
        float4 v = *(const float4*)&W[(size_t)(tk0 + lk) * NOUT + tn0 + ln + j];
        *(float4*)&tile[lk][ln + j] = v;
    }
    __syncthreads();
    const int on = t >> 2;           // n within tile
    const int ok = (t & 3) * 16;     // k chunk of 16
    unsigned short tmp[16];
#pragma unroll
    for (int j = 0; j < 16; ++j) tmp[j] = f2bf(tile[ok + j][on]);
    const int n = tn0 + on;
    const int ct = n >> 4;
    const int c = n & 15;
    const int o0 = (tk0 + ok) >> 3;
    bf16x8 lo8, hi8;
#pragma unroll
    for (int j = 0; j < 8; ++j) { lo8[j] = (short)tmp[j]; hi8[j] = (short)tmp[8 + j]; }
    *(bf16x8*)&WT[(size_t)(((ct * 128 + o0) * 16 + c)) * 8]     = lo8;
    *(bf16x8*)&WT[(size_t)(((ct * 128 + o0 + 1) * 16 + c)) * 8] = hi8;
}

// one GEMM k-step for the tile whose A sits in RBUF (XOR-swizzled LDS)
#define GEMM_STEP(RBUF)                                                        \
    {                                                                          \
        bf16x8 af = *(const bf16x8*)((RBUF) + ((abase + kstep * 64) ^ arx));   \
        _Pragma("unroll")                                                      \
        for (int fc = 0; fc < 4; ++fc) {                                       \
            bf16x8 bfr = *(const bf16x8*)(Bb[fc] + kstep * 512);               \
            acc[fc] = __builtin_amdgcn_mfma_f32_16x16x32_bf16(af, bfr,         \
                                                              acc[fc], 0, 0, 0);\
        }                                                                      \
        ++kstep;                                                               \
    }

#define WRITE_OUT(ROW0)                                                        \
    _Pragma("unroll")                                                          \
    for (int fc = 0; fc < 4; ++fc) {                                           \
        int col = w * 64 + fc * 16 + fr;                                       \
        float bv = bias[col];                                                  \
        _Pragma("unroll")                                                      \
        for (int e = 0; e < 4; ++e)                                            \
            out[(size_t)((ROW0) + gq * 4 + e) * NOUT + col] = acc[fc][e] + bv; \
    }

// Streams graphs [G0, G0+4) for this wave as one contiguous burst stream with
// in-stream boundary flushes into WBUF; INJECT runs once per 8-row burst.
#define STREAM_TILE(G0, WBUF, INJECT)                                          \
    {                                                                          \
        const int ob = offs[(G0) + (lane < 5 ? lane : 4)];                     \
        const int wave_start = __shfl(ob, 0);                                  \
        const int wave_end = __shfl(ob, 4);                                    \
        float s0[4] = {0.f,0.f,0.f,0.f}, s1[4] = {0.f,0.f,0.f,0.f};            \
        float q0[4] = {0.f,0.f,0.f,0.f}, q1[4] = {0.f,0.f,0.f,0.f};            \
        float mn[4] = {INFINITY, INFINITY, INFINITY, INFINITY};                 \
        float mx[4] = {-INFINITY, -INFINITY, -INFINITY, -INFINITY};             \
        int bidx = 0;                                                          \
        int seg_start = wave_start;                                            \
        int next_b = __shfl(ob, 1);                                            \
        char* lbase = (char*)(WBUF);                                           \
        auto flush = [&]() {                                                   \
            const int bend = __shfl(ob, bidx + 1);                             \
            const int cnt = bend - seg_start;                                  \
            const float cf = (float)cnt;                                       \
            const float inv = cnt > 0 ? 1.f / cf : 0.f;                        \
            const float invm1 = 1.f / fmaxf(cf - 1.f, 1.f);                    \
            float mean[4], sd[4];                                              \
            _Pragma("unroll")                                                  \
            for (int i = 0; i < 4; ++i) {                                      \
                float s = s0[i] + s1[i];                                       \
                float q = q0[i] + q1[i];                                       \
                mean[i] = s * inv;                                             \
                float var = (q - mean[i] * s) * invm1;                         \
                sd[i] = sqrtf(fmaxf(var, 0.f));                                \
                if (cnt == 0) { mn[i] = 0.f; mx[i] = 0.f; }                    \
            }                                                                  \
            const int lr = w * 4 + bidx;                                       \
            const unsigned int rx = (unsigned int)((lr & 7) << 4);             \
            const unsigned int b0 = (unsigned int)(lr * 2048 + lane * 8);      \
            *(uint2*)(lbase + ((b0 + 0)    ^ rx)) =                            \
                make_uint2(pack2(mean[0], mean[1]), pack2(mean[2], mean[3]));  \
            *(uint2*)(lbase + ((b0 + 512)  ^ rx)) =                            \
                make_uint2(pack2(mn[0], mn[1]), pack2(mn[2], mn[3]));          \
            *(uint2*)(lbase + ((b0 + 1024) ^ rx)) =                            \
                make_uint2(pack2(mx[0], mx[1]), pack2(mx[2], mx[3]));          \
            *(uint2*)(lbase + ((b0 + 1536) ^ rx)) =                            \
                make_uint2(pack2(sd[0], sd[1]), pack2(sd[2], sd[3]));          \
            _Pragma("unroll")                                                  \
            for (int i = 0; i < 4; ++i) {                                      \
                s0[i] = 0.f; s1[i] = 0.f; q0[i] = 0.f; q1[i] = 0.f;            \
                mn[i] = INFINITY; mx[i] = -INFINITY;                           \
            }                                                                  \
            seg_start = bend;                                                  \
            ++bidx;                                                            \
            next_b = __shfl(ob, bidx < 4 ? bidx + 1 : 4);                      \
        };                                                                     \
        int r = wave_start;                                                    \
        for (; r + 8 <= wave_end; r += 8) {                                    \
            f32x4 v[8];                                                        \
            _Pragma("unroll")                                                  \
            for (int j = 0; j < 8; ++j)                                        \
                v[j] = __builtin_nontemporal_load(hv + (size_t)(r + j) * 64 + lane); \
            INJECT;                                                            \
            _Pragma("unroll")                                                  \
            for (int j = 0; j < 8; ++j) {                                      \
                while (r + j == next_b && bidx < 3) flush();                   \
                if (j & 1) {                                                   \
                    _Pragma("unroll")                                          \
                    for (int i = 0; i < 4; ++i) {                              \
                        s1[i] += v[j][i]; q1[i] = fmaf(v[j][i], v[j][i], q1[i]); \
                        mn[i] = fminf(mn[i], v[j][i]);                         \
                        mx[i] = fmaxf(mx[i], v[j][i]);                         \
                    }                                                          \
                } else {                                                       \
                    _Pragma("unroll")                                          \
                    for (int i = 0; i < 4; ++i) {                              \
                        s0[i] += v[j][i]; q0[i] = fmaf(v[j][i], v[j][i], q0[i]); \
                        mn[i] = fminf(mn[i], v[j][i]);                         \
                        mx[i] = fmaxf(mx[i], v[j][i]);                         \
                    }                                                          \
                }                                                              \
            }                                                                  \
        }                                                                      \
        for (; r < wave_end; ++r) {                                            \
            f32x4 a = __builtin_nontemporal_load(hv + (size_t)r * 64 + lane);  \
            while (r == next_b && bidx < 3) flush();                           \
            _Pragma("unroll")                                                  \
            for (int i = 0; i < 4; ++i) {                                      \
                s0[i] += a[i]; q0[i] = fmaf(a[i], a[i], q0[i]);                \
                mn[i] = fminf(mn[i], a[i]); mx[i] = fmaxf(mx[i], a[i]);        \
            }                                                                  \
        }                                                                      \
        while (bidx < 4) flush();                                              \
    }

// Fused stats+GEMM, 2 tiles/block. 256 blocks x 256 threads (4 waves).
// Block b owns graphs [32b, 32b+32) as tiles t0=[32b,+16), t1=[32b+16,+16).
// LDS A-tiles [16][1024] bf16 with byte^=((row&7)<<4) swizzle
// (conflict-free ds_write_b64 + ds_read_b128). Wave w streams 4 graphs per
// tile and computes out cols [64w..+64) for all 16 rows of each tile.
__global__ __launch_bounds__(256) void fused_kernel(const float* __restrict__ h,
                                                    const int* __restrict__ offs,
                                                    const unsigned short* __restrict__ BT,
                                                    const float* __restrict__ bias,
                                                    float* __restrict__ out) {
    __shared__ unsigned short As[2][16 * 1024];  // 2 x 32 KB
    const int w = threadIdx.x >> 6;
    const int lane = threadIdx.x & 63;
    const int g0 = (int)blockIdx.x * 32 + w * 4;
    const f32x4* __restrict__ hv = (const f32x4*)h;  // 64 f32x4 per row

    // per-wave GEMM addressing (constant across tiles)
    const int fr = lane & 15;   // A row / B col within frag
    const int gq = lane >> 4;   // k octet within 32-k step
    const unsigned int arx = (unsigned int)((fr & 7) << 4);
    const unsigned int abase = (unsigned int)(fr * 2048 + gq * 16);
    const unsigned short* Bb[4];
#pragma unroll
    for (int fc = 0; fc < 4; ++fc)
        Bb[fc] = BT + ((((size_t)(w * 4 + fc) * 128 + gq) * 16 + fr) << 3);

    f32x4 acc[4];
    int kstep;

    // ---- Phase A: stats(tile0) -> buf0 ----
    STREAM_TILE(g0, As[0], {});
    __syncthreads();

    // ---- Phase B: stats(tile1) -> buf1, GEMM(tile0) injected ----
#pragma unroll
    for (int fc = 0; fc < 4; ++fc) acc[fc] = (f32x4){0.f, 0.f, 0.f, 0.f};
    kstep = 0;
    const char* rbuf0 = (const char*)As[0];
    STREAM_TILE(g0 + 16, As[1], { if (kstep < 32) GEMM_STEP(rbuf0); });
    while (kstep < 32) GEMM_STEP(rbuf0);
    WRITE_OUT((size_t)blockIdx.x * 32);
    __syncthreads();

    // ---- Phase C: GEMM(tile1) drain ----
#pragma unroll
    for (int fc = 0; fc < 4; ++fc) acc[fc] = (f32x4){0.f, 0.f, 0.f, 0.f};
    kstep = 0;
    const char* rbuf1 = (const char*)As[1];
    while (kstep < 32) GEMM_STEP(rbuf1);
    WRITE_OUT((size_t)blockIdx.x * 32 + 16);
}

extern "C" void kernel_launch(void* const* d_in, const int* in_sizes, int n_in,
                              void* d_out, int out_size, void* d_ws, size_t ws_size,
                              hipStream_t stream) {
    const float* h     = (const float*)d_in[0];
    const int*   batch = (const int*)d_in[1];
    const float* W     = (const float*)d_in[2];
    const float* b     = (const float*)d_in[3];
    float* out = (float*)d_out;

    const int N = in_sizes[0] / DIM;  // 500000 (unambiguous regardless of batch dtype)

    // workspace layout
    char* ws = (char*)d_ws;
    unsigned short* WT = (unsigned short*)ws;      // B': 256*1024 bf16 = 512 KB
    int* offs = (int*)(ws + 524288);               // 8193 ints

    prep_kernel<<<97, 256, 0, stream>>>(W, batch, N, WT, offs);
    fused_kernel<<<NG / 32, 256, 0, stream>>>(h, offs, WT, b, out);
}

// Round 9
// 97.818 us; speedup vs baseline: 1.1772x; 1.1772x over previous
//
#include <hip/hip_runtime.h>
#include <hip/hip_bf16.h>

// NodeToGlobal: per-graph segment {mean,min,max,std} over sorted batch ids,
// concat -> [G, 4D] -> @ W [4D, Gdim] + b.
// N=500000, D=256, G=8192, 4D=1024, Gdim=256.
//
// Structure (R6 winner + scatter-offsets prep):
//   prep: blocks [0,64)  : W -> B' (MFMA-octet bf16) via LDS transpose.
//         blocks [64,...): offsets by boundary-scatter over sorted batch
//                          (no dependent-load binary searches).
//   fused: 512 blocks x 256 thr; per block 16 graphs: stats streamed as one
//          contiguous 8-row-burst stream per wave (in-stream boundary
//          flushes), bf16 A-tile in XOR-swizzled LDS, then 16x256 MFMA GEMM
//          from LDS-A + L2-resident B'.
//
// Octet layout (coalesced MFMA fragments): X'[tile16][o][r][e] holds
// X[tile16*16 + r][o*8 + e].

#define DIM 256
#define NG 8192
#define KD 1024   // 4*DIM
#define NOUT 256  // g_dim

typedef __attribute__((ext_vector_type(8))) short bf16x8;
typedef __attribute__((ext_vector_type(4))) float f32x4;

__device__ __forceinline__ unsigned short f2bf(float x) {
    // round-to-nearest-even fp32 -> bf16 (finite inputs only)
    unsigned int u = __float_as_uint(x);
    u += 0x7fffu + ((u >> 16) & 1u);
    return (unsigned short)(u >> 16);
}

__device__ __forceinline__ unsigned int pack2(float a, float b) {
    return (unsigned int)f2bf(a) | ((unsigned int)f2bf(b) << 16);
}

// prep: blocks [0,64): W -> B' octet bf16 (LDS 64x64 transpose tiles);
//       blocks [64,..): offs scatter — thread i writes offs[g]=i for every
//       boundary g in (batch[i-1], batch[i]] (lower_bound semantics).
__global__ __launch_bounds__(256) void prep_kernel(const float* __restrict__ W,
                                                   const int* __restrict__ batch,
                                                   int N,
                                                   unsigned short* __restrict__ WT,
                                                   int* __restrict__ offs) {
    __shared__ float tile[64][68];

    if (blockIdx.x >= 64) {
        const int i = ((int)blockIdx.x - 64) * 256 + (int)threadIdx.x;
        if (i >= N) return;
        // int64 detection: word[N-1] is the hi-word of element (N-1)/2 when
        // batch is int64 (== 0 since ids < 8192); for int32 it's the max id.
        const bool is64 = (batch[N - 1] == 0);
        const int cur = is64 ? batch[2 * i] : batch[i];
        const int prev = (i == 0) ? -1 : (is64 ? batch[2 * (i - 1)] : batch[i - 1]);
        for (int g = prev + 1; g <= cur; ++g) offs[g] = i;   // first idx with batch>=g
        if (i == N - 1)
            for (int g = cur + 1; g <= NG; ++g) offs[g] = N; // trailing empties + offs[NG]
        return;
    }

    // ---- W transpose + bf16 cast into B' octet layout ----
    const int t = threadIdx.x;
    const int tk0 = ((int)blockIdx.x & 15) * 64;  // 16 k-tiles
    const int tn0 = ((int)blockIdx.x >> 4) * 64;  // 4 n-tiles
    const int lk = t >> 2;
    const int ln = (t & 3) * 16;
#pragma unroll
    for (int j = 0; j < 16; j += 4) {
        float4 v = *(const float4*)&W[(size_t)(tk0 + lk) * NOUT + tn0 + ln + j];
        *(float4*)&tile[lk][ln + j] = v;
    }
    __syncthreads();
    const int on = t >> 2;           // n within tile
    const int ok = (t & 3) * 16;     // k chunk of 16
    unsigned short tmp[16];
#pragma unroll
    for (int j = 0; j < 16; ++j) tmp[j] = f2bf(tile[ok + j][on]);
    const int n = tn0 + on;
    const int ct = n >> 4;
    const int c = n & 15;
    const int o0 = (tk0 + ok) >> 3;
    bf16x8 lo8, hi8;
#pragma unroll
    for (int j = 0; j < 8; ++j) { lo8[j] = (short)tmp[j]; hi8[j] = (short)tmp[8 + j]; }
    *(bf16x8*)&WT[(size_t)(((ct * 128 + o0) * 16 + c)) * 8]     = lo8;
    *(bf16x8*)&WT[(size_t)(((ct * 128 + o0 + 1) * 16 + c)) * 8] = hi8;
}

// Fused stats+GEMM. 512 blocks x 256 threads (4 waves). Block owns graphs
// [16b, 16b+16); wave w owns graphs 16b+4w..+3 streamed as one contiguous
// row range with in-stream boundary flushes. LDS A-tile [16][1024] bf16,
// byte^=((row&7)<<4) swizzle (conflict-free ds_write_b64 + ds_read_b128).
// After barrier, wave w computes out rows [0..16) x cols [64w..+64).
__global__ __launch_bounds__(256) void fused_kernel(const float* __restrict__ h,
                                                    const int* __restrict__ offs,
                                                    const unsigned short* __restrict__ BT,
                                                    const float* __restrict__ bias,
                                                    float* __restrict__ out) {
    __shared__ unsigned short As[16 * 1024];  // 32 KB
    const int w = threadIdx.x >> 6;
    const int lane = threadIdx.x & 63;
    const int tile = blockIdx.x;
    const int g0 = tile * 16 + w * 4;

    // lanes 0..4 hold offs[g0+lane]; boundaries are wave-uniform via shfl.
    const int ob = offs[g0 + (lane < 5 ? lane : 4)];
    const int wave_start = __shfl(ob, 0);
    const int wave_end = __shfl(ob, 4);

    float s0[4] = {0.f,0.f,0.f,0.f}, s1[4] = {0.f,0.f,0.f,0.f};
    float q0[4] = {0.f,0.f,0.f,0.f}, q1[4] = {0.f,0.f,0.f,0.f};
    float mn[4] = {INFINITY, INFINITY, INFINITY, INFINITY};
    float mx[4] = {-INFINITY, -INFINITY, -INFINITY, -INFINITY};

    int bidx = 0;              // graph (row) index within this wave's 4
    int seg_start = wave_start;
    int next_b = __shfl(ob, 1);

    char* lbase = (char*)As;
    // flush: finalize graph bidx with rows [seg_start, bend) and write its
    // bf16 LDS row; reset accumulators; advance boundary bookkeeping.
    auto flush = [&]() {
        const int bend = __shfl(ob, bidx + 1);
        const int cnt = bend - seg_start;
        const float cf = (float)cnt;
        const float inv = cnt > 0 ? 1.f / cf : 0.f;
        const float invm1 = 1.f / fmaxf(cf - 1.f, 1.f);
        float mean[4], sd[4];
#pragma unroll
        for (int i = 0; i < 4; ++i) {
            float s = s0[i] + s1[i];
            float q = q0[i] + q1[i];
            mean[i] = s * inv;                           // 0 when empty
            float var = (q - mean[i] * s) * invm1;       // unbiased
            sd[i] = sqrtf(fmaxf(var, 0.f));
            if (cnt == 0) { mn[i] = 0.f; mx[i] = 0.f; }
        }
        const int lr = w * 4 + bidx;
        const unsigned int rx = (unsigned int)((lr & 7) << 4);
        const unsigned int b0 = (unsigned int)(lr * 2048 + lane * 8);
        *(uint2*)(lbase + ((b0 + 0)    ^ rx)) = make_uint2(pack2(mean[0], mean[1]), pack2(mean[2], mean[3]));
        *(uint2*)(lbase + ((b0 + 512)  ^ rx)) = make_uint2(pack2(mn[0], mn[1]),     pack2(mn[2], mn[3]));
        *(uint2*)(lbase + ((b0 + 1024) ^ rx)) = make_uint2(pack2(mx[0], mx[1]),     pack2(mx[2], mx[3]));
        *(uint2*)(lbase + ((b0 + 1536) ^ rx)) = make_uint2(pack2(sd[0], sd[1]),     pack2(sd[2], sd[3]));
#pragma unroll
        for (int i = 0; i < 4; ++i) {
            s0[i] = 0.f; s1[i] = 0.f; q0[i] = 0.f; q1[i] = 0.f;
            mn[i] = INFINITY; mx[i] = -INFINITY;
        }
        seg_start = bend;
        ++bidx;
        next_b = __shfl(ob, bidx < 4 ? bidx + 1 : 4);
    };

    const f32x4* __restrict__ hv = (const f32x4*)h;  // 64 f32x4 per row
    int r = wave_start;
    for (; r + 8 <= wave_end; r += 8) {
        f32x4 v[8];
#pragma unroll
        for (int j = 0; j < 8; ++j)
            v[j] = __builtin_nontemporal_load(hv + (size_t)(r + j) * 64 + lane);
#pragma unroll
        for (int j = 0; j < 8; ++j) {
            while (r + j == next_b && bidx < 3) flush();  // uniform, rare
            if (j & 1) {
#pragma unroll
                for (int i = 0; i < 4; ++i) {
                    s1[i] += v[j][i]; q1[i] = fmaf(v[j][i], v[j][i], q1[i]);
                    mn[i] = fminf(mn[i], v[j][i]); mx[i] = fmaxf(mx[i], v[j][i]);
                }
            } else {
#pragma unroll
                for (int i = 0; i < 4; ++i) {
                    s0[i] += v[j][i]; q0[i] = fmaf(v[j][i], v[j][i], q0[i]);
                    mn[i] = fminf(mn[i], v[j][i]); mx[i] = fmaxf(mx[i], v[j][i]);
                }
            }
        }
    }
    for (; r < wave_end; ++r) {
        f32x4 a = __builtin_nontemporal_load(hv + (size_t)r * 64 + lane);
        while (r == next_b && bidx < 3) flush();
#pragma unroll
        for (int i = 0; i < 4; ++i) {
            s0[i] += a[i]; q0[i] = fmaf(a[i], a[i], q0[i]);
            mn[i] = fminf(mn[i], a[i]); mx[i] = fmaxf(mx[i], a[i]);
        }
    }
    while (bidx < 4) flush();  // last graph + trailing empty graphs

    __syncthreads();

    // ---- GEMM: rows [0,16) x cols [64w..+64) ----
    const int fr = lane & 15;   // A row / B col within frag
    const int gq = lane >> 4;   // k octet within 32-k step
    const unsigned int arx = (unsigned int)((fr & 7) << 4);
    const unsigned int abase = (unsigned int)(fr * 2048 + gq * 16);

    f32x4 acc[4] = {{0.f,0.f,0.f,0.f},{0.f,0.f,0.f,0.f},{0.f,0.f,0.f,0.f},{0.f,0.f,0.f,0.f}};

    const unsigned short* Bb[4];
#pragma unroll
    for (int fc = 0; fc < 4; ++fc)
        Bb[fc] = BT + ((((size_t)(w * 4 + fc) * 128 + gq) * 16 + fr) << 3);

#pragma unroll 2
    for (int t = 0; t < 32; ++t) {
        bf16x8 af = *(const bf16x8*)((const char*)As + ((abase + t * 64) ^ arx));
#pragma unroll
        for (int fc = 0; fc < 4; ++fc) {
            bf16x8 bfr = *(const bf16x8*)(Bb[fc] + t * 512);
            acc[fc] = __builtin_amdgcn_mfma_f32_16x16x32_bf16(af, bfr, acc[fc], 0, 0, 0);
        }
    }

    const size_t row0 = (size_t)tile * 16;
#pragma unroll
    for (int fc = 0; fc < 4; ++fc) {
        int col = w * 64 + fc * 16 + fr;
        float bv = bias[col];
#pragma unroll
        for (int e = 0; e < 4; ++e) {
            size_t row = row0 + gq * 4 + e;
            out[row * NOUT + col] = acc[fc][e] + bv;
        }
    }
}

extern "C" void kernel_launch(void* const* d_in, const int* in_sizes, int n_in,
                              void* d_out, int out_size, void* d_ws, size_t ws_size,
                              hipStream_t stream) {
    const float* h     = (const float*)d_in[0];
    const int*   batch = (const int*)d_in[1];
    const float* W     = (const float*)d_in[2];
    const float* b     = (const float*)d_in[3];
    float* out = (float*)d_out;

    const int N = in_sizes[0] / DIM;  // 500000 (unambiguous regardless of batch dtype)

    // workspace layout
    char* ws = (char*)d_ws;
    unsigned short* WT = (unsigned short*)ws;      // B': 256*1024 bf16 = 512 KB
    int* offs = (int*)(ws + 524288);               // 8193 ints

    const int scatter_blocks = (N + 255) / 256;    // 1954
    prep_kernel<<<64 + scatter_blocks, 256, 0, stream>>>(W, batch, N, WT, offs);
    fused_kernel<<<NG / 16, 256, 0, stream>>>(h, offs, WT, b, out);
}